// Round 1
// baseline (2105.055 us; speedup 1.0000x reference)
//
#include <hip/hip_runtime.h>

// ---------------------------------------------------------------------------
// CompGCN-style network, all-f32 baseline.
//   sizes: N=100000 ents, E=400000 edges (+N self loops), D=200, D0=100,
//          NREL=475, B=1024 queries, L=2 layers
// Scratch plan:
//   d_ws  (~82.3 MB): ent[N*D], relA, relB, transposed weights, q, scale/shift, bsum
//   d_out (410 MB, front ~89 MB as temp): agg/tmp[N*D], CSR arrays, stat partials
//   (everything in d_out is dead before the final score GEMM rewrites all of it)
// ---------------------------------------------------------------------------

#define N_ENT  100000
#define N_EDGE 400000
#define N_EF   500000   // N_EDGE + N_ENT self loops
#define D_     200
#define D0_    100
#define NREL_  475
#define B_     1024
#define GSTAT  1024     // blocks in column-stats pass

// ---------------- small utility kernels ----------------

__global__ void k_transpose(const float* __restrict__ s, float* __restrict__ d, int R, int C) {
  int i = blockIdx.x * 256 + threadIdx.x;
  if (i < R * C) { int r = i / C, c = i - r * C; d[c * R + r] = s[i]; }
}

__global__ void k_hist(const int* __restrict__ dst_id, int* __restrict__ cnt) {
  int e = blockIdx.x * 256 + threadIdx.x;
  if (e < N_EF) {
    int d = (e < N_EDGE) ? dst_id[e] : (e - N_EDGE);
    atomicAdd(&cnt[d], 1);
  }
}

__global__ __launch_bounds__(256) void k_scan_block(const int* __restrict__ cnt,
                                                    int* __restrict__ rp,
                                                    int* __restrict__ bsum) {
  __shared__ int sm[256];
  int tid = threadIdx.x;
  int base = blockIdx.x * 1024 + tid * 4;
  int v0 = (base + 0 < N_ENT) ? cnt[base + 0] : 0;
  int v1 = (base + 1 < N_ENT) ? cnt[base + 1] : 0;
  int v2 = (base + 2 < N_ENT) ? cnt[base + 2] : 0;
  int v3 = (base + 3 < N_ENT) ? cnt[base + 3] : 0;
  int tsum = v0 + v1 + v2 + v3;
  sm[tid] = tsum;
  __syncthreads();
  for (int off = 1; off < 256; off <<= 1) {
    int t = (tid >= off) ? sm[tid - off] : 0;
    __syncthreads();
    sm[tid] += t;
    __syncthreads();
  }
  int run = sm[tid] - tsum;  // exclusive within block
  if (base + 0 < N_ENT) { rp[base + 0] = run; } run += v0;
  if (base + 1 < N_ENT) { rp[base + 1] = run; } run += v1;
  if (base + 2 < N_ENT) { rp[base + 2] = run; } run += v2;
  if (base + 3 < N_ENT) { rp[base + 3] = run; }
  if (tid == 255) bsum[blockIdx.x] = sm[255];
}

__global__ void k_scan_tops(int* __restrict__ bsum, int nb) {
  __shared__ int sm[256];
  int tid = threadIdx.x;
  int v = (tid < nb) ? bsum[tid] : 0;
  sm[tid] = v;
  __syncthreads();
  for (int off = 1; off < 256; off <<= 1) {
    int t = (tid >= off) ? sm[tid - off] : 0;
    __syncthreads();
    sm[tid] += t;
    __syncthreads();
  }
  if (tid < nb) bsum[tid] = sm[tid] - v;  // exclusive
}

__global__ void k_scan_add(int* __restrict__ rp, const int* __restrict__ bsum,
                           int* __restrict__ cursor) {
  int i = blockIdx.x * 256 + threadIdx.x;
  if (i < N_ENT) {
    int r = rp[i] + bsum[i >> 10];
    rp[i] = r;
    cursor[i] = r;
  }
}

__global__ void k_fill(const int* __restrict__ src_id, const int* __restrict__ dst_id,
                       const int* __restrict__ e_type, int* __restrict__ cursor,
                       int* __restrict__ cs, int* __restrict__ ct) {
  int e = blockIdx.x * 256 + threadIdx.x;
  if (e < N_EF) {
    int s, d, t;
    if (e < N_EDGE) { s = src_id[e]; d = dst_id[e]; t = e_type[e]; }
    else            { s = e - N_EDGE; d = s; t = NREL_ - 1; }
    int pos = atomicAdd(&cursor[d], 1);
    cs[pos] = s;
    ct[pos] = t;
  }
}

// one block per node: tmp[n][f] = sum over in-edges of ent[src][f]*relE[et][f]
__global__ __launch_bounds__(256) void k_aggregate(const float* __restrict__ ent,
                                                   const float* __restrict__ relE,
                                                   const int* __restrict__ rp,
                                                   const int* __restrict__ cnt,
                                                   const int* __restrict__ cs,
                                                   const int* __restrict__ ct,
                                                   float* __restrict__ out) {
  int n = blockIdx.x;
  int f = threadIdx.x;
  if (f >= D_) return;
  int s0 = rp[n], e0 = s0 + cnt[n];
  float acc = 0.f;
  for (int idx = s0; idx < e0; ++idx) {
    int s = cs[idx];
    int t = ct[idx];
    acc = fmaf(ent[(long)s * D_ + f], relE[(long)t * D_ + f], acc);
  }
  out[(long)n * D_ + f] = acc;
}

// column sums / sumsq in f64, two-stage deterministic reduction
__global__ __launch_bounds__(256) void k_colstats(const float* __restrict__ X,
                                                  double* __restrict__ part) {
  int f = threadIdx.x;
  if (f >= D_) return;
  double s = 0.0, s2 = 0.0;
  for (int r = blockIdx.x; r < N_ENT; r += GSTAT) {
    float v = X[(long)r * D_ + f];
    s += v;
    s2 += (double)v * v;
  }
  part[(long)blockIdx.x * (2 * D_) + f] = s;
  part[(long)blockIdx.x * (2 * D_) + D_ + f] = s2;
}

__global__ void k_bn_fin(const double* __restrict__ part, const float* __restrict__ g,
                         const float* __restrict__ b, float* __restrict__ scale,
                         float* __restrict__ shift) {
  int f = threadIdx.x;
  if (f >= D_) return;
  double S = 0.0, S2 = 0.0;
#pragma unroll 4
  for (int i = 0; i < GSTAT; i++) {
    S += part[(long)i * (2 * D_) + f];
    S2 += part[(long)i * (2 * D_) + D_ + f];
  }
  double mean = S / N_ENT;
  double var = S2 / N_ENT - mean * mean;
  double inv = 1.0 / sqrt(var + 1e-5);
  float sc = g[f] * (float)inv;
  scale[f] = sc;
  shift[f] = b[f] - (float)mean * sc;
}

__global__ void k_norm_relu(float* __restrict__ X, const float* __restrict__ scale,
                            const float* __restrict__ shift) {
  const long total = (long)N_ENT * D_ / 4;
  for (long i4 = (long)blockIdx.x * 256 + threadIdx.x; i4 < total;
       i4 += (long)gridDim.x * 256) {
    float4 v = ((float4*)X)[i4];
    int fb = (int)((i4 * 4) % D_);  // D_ % 4 == 0 so fb..fb+3 in-range
    v.x = fmaxf(fmaf(v.x, scale[fb + 0], shift[fb + 0]), 0.f);
    v.y = fmaxf(fmaf(v.y, scale[fb + 1], shift[fb + 1]), 0.f);
    v.z = fmaxf(fmaf(v.z, scale[fb + 2], shift[fb + 2]), 0.f);
    v.w = fmaxf(fmaf(v.w, scale[fb + 3], shift[fb + 3]), 0.f);
    ((float4*)X)[i4] = v;
  }
}

__global__ void k_build_q(const float* __restrict__ ent, const float* __restrict__ relE,
                          const int* __restrict__ subj, const int* __restrict__ rel,
                          float* __restrict__ q) {
  int i = blockIdx.x * 256 + threadIdx.x;
  if (i < B_ * D_) {
    int b = i / D_, f = i - b * D_;
    q[i] = ent[(long)subj[b] * D_ + f] * relE[(long)rel[b] * D_ + f];
  }
}

// ---------------- tiled f32 GEMM: C[M,Nc] = A[M,K] @ Bm[Nc,K]^T ----------------
// 256 threads (tx=tid&15, ty=tid>>4); block tile BM x 64; thread tile TM x TN with
// row map i*16+ty / col map j*16+tx (keeps LDS reads at <=2-way conflicts, free).
// PRO_BN: y = relu(x*scale[k]+shift[k]) applied to A during LDS staging.
template <int TM, int TN, bool PRO_BN, bool HAS_BIAS>
__global__ __launch_bounds__(256) void k_gemm_abt(
    const float* __restrict__ A, const float* __restrict__ Bm, float* __restrict__ C,
    int M, int Nc, int K, long ldc, const float* __restrict__ scale,
    const float* __restrict__ shift, const float* __restrict__ bias) {
  constexpr int BM = TM * 16, BN = TN * 16, KC = 20;
  __shared__ float As[BM * KC];
  __shared__ float Bs[BN * KC];
  const int tid = threadIdx.x;
  const int tx = tid & 15, ty = tid >> 4;
  const int bm = blockIdx.x * BM, bn = blockIdx.y * BN;

  float acc[TM][TN];
#pragma unroll
  for (int i = 0; i < TM; i++)
#pragma unroll
    for (int j = 0; j < TN; j++) acc[i][j] = 0.f;

  for (int kc = 0; kc < K; kc += KC) {
    // stage A tile (BM x KC) as float4s
    for (int i4 = tid; i4 < BM * 5; i4 += 256) {
      int r = i4 / 5, kq = (i4 - r * 5) * 4;
      int row = bm + r;
      if (row > M - 1) row = M - 1;
      float4 v = *(const float4*)(A + (long)row * K + kc + kq);
      if (PRO_BN) {
        int kk = kc + kq;
        v.x = fmaxf(fmaf(v.x, scale[kk + 0], shift[kk + 0]), 0.f);
        v.y = fmaxf(fmaf(v.y, scale[kk + 1], shift[kk + 1]), 0.f);
        v.z = fmaxf(fmaf(v.z, scale[kk + 2], shift[kk + 2]), 0.f);
        v.w = fmaxf(fmaf(v.w, scale[kk + 3], shift[kk + 3]), 0.f);
      }
      *(float4*)(As + r * KC + kq) = v;
    }
    // stage B tile (BN x KC)
    for (int i4 = tid; i4 < BN * 5; i4 += 256) {
      int r = i4 / 5, kq = (i4 - r * 5) * 4;
      int row = bn + r;
      if (row > Nc - 1) row = Nc - 1;
      float4 v = *(const float4*)(Bm + (long)row * K + kc + kq);
      *(float4*)(Bs + r * KC + kq) = v;
    }
    __syncthreads();
#pragma unroll
    for (int k4 = 0; k4 < KC; k4 += 4) {
      float4 af[TM], bf[TN];
#pragma unroll
      for (int i = 0; i < TM; i++) af[i] = *(const float4*)(As + (i * 16 + ty) * KC + k4);
#pragma unroll
      for (int j = 0; j < TN; j++) bf[j] = *(const float4*)(Bs + (j * 16 + tx) * KC + k4);
#pragma unroll
      for (int i = 0; i < TM; i++)
#pragma unroll
        for (int j = 0; j < TN; j++) {
          acc[i][j] = fmaf(af[i].x, bf[j].x, acc[i][j]);
          acc[i][j] = fmaf(af[i].y, bf[j].y, acc[i][j]);
          acc[i][j] = fmaf(af[i].z, bf[j].z, acc[i][j]);
          acc[i][j] = fmaf(af[i].w, bf[j].w, acc[i][j]);
        }
    }
    __syncthreads();
  }
#pragma unroll
  for (int i = 0; i < TM; i++) {
    int m = bm + i * 16 + ty;
    if (m >= M) continue;
#pragma unroll
    for (int j = 0; j < TN; j++) {
      int n = bn + j * 16 + tx;
      if (n >= Nc) continue;
      float v = acc[i][j];
      if (HAS_BIAS) v += bias[n];
      C[(long)m * ldc + n] = v;
    }
  }
}

// ---------------------------------------------------------------------------

extern "C" void kernel_launch(void* const* d_in, const int* in_sizes, int n_in,
                              void* d_out, int out_size, void* d_ws, size_t ws_size,
                              hipStream_t stream) {
  const int* src_id = (const int*)d_in[0];
  const int* dst_id = (const int*)d_in[1];
  const int* e_type = (const int*)d_in[2];
  const int* subj = (const int*)d_in[3];
  const int* rel = (const int*)d_in[4];
  const float* emb_h = (const float*)d_in[5];
  const float* emb_e = (const float*)d_in[6];
  const float* lin_w = (const float*)d_in[7];
  const float* lin_b = (const float*)d_in[8];
  const float* rel_wt = (const float*)d_in[9];
  const float* w_rel = (const float*)d_in[10];
  const float* agg_bn_g = (const float*)d_in[11];
  const float* agg_bn_b = (const float*)d_in[12];
  const float* cell_bn_g = (const float*)d_in[13];
  const float* cell_bn_b = (const float*)d_in[14];
  const float* concat_w = (const float*)d_in[15];
  const float* concat_b = (const float*)d_in[16];
  float* out = (float*)d_out;

  // ---- scratch carving: d_ws ----
  char* w = (char*)d_ws;
  float* ent   = (float*)(w + 0);           // 80,000,000 B
  float* relA  = (float*)(w + 80000000);    //    380,000
  float* relB  = (float*)(w + 80380000);    //    380,000
  float* linwT = (float*)(w + 80760000);    //     80,000  [200][100]
  float* embeT = (float*)(w + 80840000);    //     80,000  [200][100]
  float* cw0T  = (float*)(w + 80920000);    //    160,000  [200][200]
  float* cw1T  = (float*)(w + 81080000);    //    160,000
  float* wrT   = (float*)(w + 81240000);    //    160,000
  float* qbuf  = (float*)(w + 81400000);    //    819,200  [1024][200]
  float* scaleb = (float*)(w + 82219200);   //        800
  float* shiftb = (float*)(w + 82220000);   //        800
  int*   bsum   = (int*)(w + 82220800);     //      2,048

  // ---- scratch carving: front of d_out (dead before final score GEMM) ----
  char* ob = (char*)d_out;
  float* tmp     = (float*)(ob + 0);          // 80,000,000  agg / pre-BN h
  int* counts    = (int*)(ob + 80000000);     //    400,000
  int* row_ptr   = (int*)(ob + 80400000);     //    400,000
  int* cursor    = (int*)(ob + 80800000);     //    400,000
  int* csr_src   = (int*)(ob + 81200000);     //  2,000,000
  int* csr_et    = (int*)(ob + 83200000);     //  2,000,000
  double* part   = (double*)(ob + 85200000);  //  3,276,800

  // ---- CSR build (per-destination) ----
  hipMemsetAsync(counts, 0, N_ENT * sizeof(int), stream);
  k_hist<<<(N_EF + 255) / 256, 256, 0, stream>>>(dst_id, counts);
  const int NB = (N_ENT + 1023) / 1024;  // 98
  k_scan_block<<<NB, 256, 0, stream>>>(counts, row_ptr, bsum);
  k_scan_tops<<<1, 256, 0, stream>>>(bsum, NB);
  k_scan_add<<<(N_ENT + 255) / 256, 256, 0, stream>>>(row_ptr, bsum, cursor);
  k_fill<<<(N_EF + 255) / 256, 256, 0, stream>>>(src_id, dst_id, e_type, cursor,
                                                 csr_src, csr_et);

  // ---- weight transposes (Bm side of A@B^T GEMMs) ----
  k_transpose<<<(D0_ * D_ + 255) / 256, 256, 0, stream>>>(lin_w, linwT, D0_, D_);
  k_transpose<<<(D0_ * D_ + 255) / 256, 256, 0, stream>>>(emb_e, embeT, D0_, D_);
  k_transpose<<<(D_ * D_ + 255) / 256, 256, 0, stream>>>(concat_w, cw0T, D_, D_);
  k_transpose<<<(D_ * D_ + 255) / 256, 256, 0, stream>>>(concat_w + D_ * D_, cw1T, D_, D_);
  k_transpose<<<(D_ * D_ + 255) / 256, 256, 0, stream>>>(w_rel, wrT, D_, D_);

  // ---- init projections ----
  const int GM = (N_ENT + 127) / 128;  // 782
  k_gemm_abt<8, 4, false, true><<<dim3(GM, 4), 256, 0, stream>>>(
      emb_h, linwT, ent, N_ENT, D_, D0_, (long)D_, nullptr, nullptr, lin_b);
  k_gemm_abt<8, 4, false, false><<<dim3(4, 4), 256, 0, stream>>>(
      rel_wt, embeT, relA, NREL_, D_, D0_, (long)D_, nullptr, nullptr, nullptr);

  float* relCur = relA;
  float* relNxt = relB;
  for (int i = 0; i < 2; i++) {
    // edge gather-multiply-scatter (segment sum via CSR)
    k_aggregate<<<N_ENT, 256, 0, stream>>>(ent, relCur, row_ptr, counts, csr_src,
                                           csr_et, tmp);
    // agg BN stats -> fused into concat GEMM prologue (BN+ReLU on A while staging)
    k_colstats<<<GSTAT, 256, 0, stream>>>(tmp, part);
    k_bn_fin<<<1, 256, 0, stream>>>(part, agg_bn_g + i * D_, agg_bn_b + i * D_,
                                    scaleb, shiftb);
    k_gemm_abt<8, 4, true, true><<<dim3(GM, 4), 256, 0, stream>>>(
        tmp, (i == 0) ? cw0T : cw1T, ent, N_ENT, D_, D_, (long)D_, scaleb, shiftb,
        concat_b + i * D_);
    // cell BN + ReLU, materialized in-place on ent
    k_colstats<<<GSTAT, 256, 0, stream>>>(ent, part);
    k_bn_fin<<<1, 256, 0, stream>>>(part, cell_bn_g + i * D_, cell_bn_b + i * D_,
                                    scaleb, shiftb);
    k_norm_relu<<<2048, 256, 0, stream>>>(ent, scaleb, shiftb);
    // rel transform for next layer / scorer
    k_gemm_abt<8, 4, false, false><<<dim3(4, 4), 256, 0, stream>>>(
        relCur, wrT, relNxt, NREL_, D_, D_, (long)D_, nullptr, nullptr, nullptr);
    float* t = relCur; relCur = relNxt; relNxt = t;
  }

  // ---- DistMult score: out[b][n] = sum_d q[b][d] * ent[n][d] ----
  k_build_q<<<(B_ * D_ + 255) / 256, 256, 0, stream>>>(ent, relCur, subj, rel, qbuf);
  k_gemm_abt<8, 4, false, false><<<dim3(B_ / 128, (N_ENT + 63) / 64), 256, 0, stream>>>(
      qbuf, ent, out, B_, N_ENT, D_, (long)N_ENT, nullptr, nullptr, nullptr);
}

// Round 2
// 1528.614 us; speedup vs baseline: 1.3771x; 1.3771x over previous
//
#include <hip/hip_runtime.h>

// ---------------------------------------------------------------------------
// CompGCN-style network. GEMMs on MFMA (split-bf16 hi/lo, 3-term ~f32 accuracy).
//   N=100000 ents, E=400000 edges (+N self loops), D=200, D0=100,
//   NREL=475, B=1024 queries, L=2 layers
// d_ws  (~90.5 MB): ent_h/ent_l [N][224] bf16, q_h/q_l [1024][224] bf16
//                   (ONLY buffers read while score GEMM writes d_out)
// d_out (410 MB, front ~260 MB as temp): ent f32, tmp f32, tmp hi/lo,
//                   emb_h hi/lo, CSR, stats, rel, weight splits
// ---------------------------------------------------------------------------

#define N_ENT  100000
#define N_EDGE 400000
#define N_EF   500000
#define D_     200
#define D0_    100
#define NREL_  475
#define B_     1024
#define GSTAT  1024
#define KP_D   224   // D padded to multiple of 32
#define KP_D0  128   // D0 padded

typedef unsigned short ushort_t;
typedef __attribute__((ext_vector_type(8))) short bf16x8;
typedef __attribute__((ext_vector_type(4))) float f32x4;

__device__ __forceinline__ ushort_t f2bf(float x) {
  unsigned u = __float_as_uint(x);
  return (ushort_t)((u + 0x7FFFu + ((u >> 16) & 1u)) >> 16);
}
__device__ __forceinline__ float bf2f(ushort_t h) {
  return __uint_as_float(((unsigned)h) << 16);
}

__device__ __forceinline__ void gld16(const void* g, void* l) {
  __builtin_amdgcn_global_load_lds(
      (const __attribute__((address_space(1))) unsigned*)g,
      (__attribute__((address_space(3))) unsigned*)l, 16, 0, 0);
}

// ---------------- CSR build ----------------

__global__ void k_hist(const int* __restrict__ dst_id, int* __restrict__ cnt) {
  int e = blockIdx.x * 256 + threadIdx.x;
  if (e < N_EF) {
    int d = (e < N_EDGE) ? dst_id[e] : (e - N_EDGE);
    atomicAdd(&cnt[d], 1);
  }
}

__global__ __launch_bounds__(256) void k_scan_block(const int* __restrict__ cnt,
                                                    int* __restrict__ rp,
                                                    int* __restrict__ bsum) {
  __shared__ int sm[256];
  int tid = threadIdx.x;
  int base = blockIdx.x * 1024 + tid * 4;
  int v0 = (base + 0 < N_ENT) ? cnt[base + 0] : 0;
  int v1 = (base + 1 < N_ENT) ? cnt[base + 1] : 0;
  int v2 = (base + 2 < N_ENT) ? cnt[base + 2] : 0;
  int v3 = (base + 3 < N_ENT) ? cnt[base + 3] : 0;
  int tsum = v0 + v1 + v2 + v3;
  sm[tid] = tsum;
  __syncthreads();
  for (int off = 1; off < 256; off <<= 1) {
    int t = (tid >= off) ? sm[tid - off] : 0;
    __syncthreads();
    sm[tid] += t;
    __syncthreads();
  }
  int run = sm[tid] - tsum;
  if (base + 0 < N_ENT) { rp[base + 0] = run; } run += v0;
  if (base + 1 < N_ENT) { rp[base + 1] = run; } run += v1;
  if (base + 2 < N_ENT) { rp[base + 2] = run; } run += v2;
  if (base + 3 < N_ENT) { rp[base + 3] = run; }
  if (tid == 255) bsum[blockIdx.x] = sm[255];
}

__global__ void k_scan_tops(int* __restrict__ bsum, int nb) {
  __shared__ int sm[256];
  int tid = threadIdx.x;
  int v = (tid < nb) ? bsum[tid] : 0;
  sm[tid] = v;
  __syncthreads();
  for (int off = 1; off < 256; off <<= 1) {
    int t = (tid >= off) ? sm[tid - off] : 0;
    __syncthreads();
    sm[tid] += t;
    __syncthreads();
  }
  if (tid < nb) bsum[tid] = sm[tid] - v;
}

__global__ void k_scan_add(int* __restrict__ rp, const int* __restrict__ bsum,
                           int* __restrict__ cursor) {
  int i = blockIdx.x * 256 + threadIdx.x;
  if (i < N_ENT) {
    int r = rp[i] + bsum[i >> 10];
    rp[i] = r;
    cursor[i] = r;
  }
}

__global__ void k_fill(const int* __restrict__ src_id, const int* __restrict__ dst_id,
                       const int* __restrict__ e_type, int* __restrict__ cursor,
                       int* __restrict__ cs, int* __restrict__ ct) {
  int e = blockIdx.x * 256 + threadIdx.x;
  if (e < N_EF) {
    int s, d, t;
    if (e < N_EDGE) { s = src_id[e]; d = dst_id[e]; t = e_type[e]; }
    else            { s = e - N_EDGE; d = s; t = NREL_ - 1; }
    int pos = atomicAdd(&cursor[d], 1);
    cs[pos] = s;
    ct[pos] = t;
  }
}

// ---------------- aggregation / BN / misc ----------------

__global__ __launch_bounds__(256) void k_aggregate(const float* __restrict__ ent,
                                                   const float* __restrict__ relE,
                                                   const int* __restrict__ rp,
                                                   const int* __restrict__ cnt,
                                                   const int* __restrict__ cs,
                                                   const int* __restrict__ ct,
                                                   float* __restrict__ out) {
  int n = blockIdx.x;
  int f = threadIdx.x;
  if (f >= D_) return;
  int s0 = rp[n], e0 = s0 + cnt[n];
  float acc = 0.f;
  for (int idx = s0; idx < e0; ++idx) {
    int s = cs[idx];
    int t = ct[idx];
    acc = fmaf(ent[(long)s * D_ + f], relE[(long)t * D_ + f], acc);
  }
  out[(long)n * D_ + f] = acc;
}

__global__ __launch_bounds__(256) void k_colstats(const float* __restrict__ X,
                                                  double* __restrict__ part) {
  int f = threadIdx.x;
  if (f >= D_) return;
  double s = 0.0, s2 = 0.0;
  for (int r = blockIdx.x; r < N_ENT; r += GSTAT) {
    float v = X[(long)r * D_ + f];
    s += v;
    s2 += (double)v * v;
  }
  part[(long)blockIdx.x * (2 * D_) + f] = s;
  part[(long)blockIdx.x * (2 * D_) + D_ + f] = s2;
}

__global__ void k_bn_fin(const double* __restrict__ part, const float* __restrict__ g,
                         const float* __restrict__ b, float* __restrict__ scale,
                         float* __restrict__ shift) {
  int f = threadIdx.x;
  if (f >= D_) return;
  double S = 0.0, S2 = 0.0;
#pragma unroll 4
  for (int i = 0; i < GSTAT; i++) {
    S += part[(long)i * (2 * D_) + f];
    S2 += part[(long)i * (2 * D_) + D_ + f];
  }
  double mean = S / N_ENT;
  double var = S2 / N_ENT - mean * mean;
  double inv = 1.0 / sqrt(var + 1e-5);
  float sc = g[f] * (float)inv;
  scale[f] = sc;
  shift[f] = b[f] - (float)mean * sc;
}

__global__ void k_norm_relu(float* __restrict__ X, const float* __restrict__ scale,
                            const float* __restrict__ shift) {
  const long total = (long)N_ENT * D_ / 4;
  for (long i4 = (long)blockIdx.x * 256 + threadIdx.x; i4 < total;
       i4 += (long)gridDim.x * 256) {
    float4 v = ((float4*)X)[i4];
    int fb = (int)((i4 * 4) % D_);
    v.x = fmaxf(fmaf(v.x, scale[fb + 0], shift[fb + 0]), 0.f);
    v.y = fmaxf(fmaf(v.y, scale[fb + 1], shift[fb + 1]), 0.f);
    v.z = fmaxf(fmaf(v.z, scale[fb + 2], shift[fb + 2]), 0.f);
    v.w = fmaxf(fmaf(v.w, scale[fb + 3], shift[fb + 3]), 0.f);
    ((float4*)X)[i4] = v;
  }
}

// ---------------- split / convert kernels ----------------

// f32 [R][K] -> bf16 hi/lo [R][Kp], zero-padded; optional fused BN+ReLU.
__global__ void k_split(const float* __restrict__ X, int R, int K, int Kp,
                        ushort_t* __restrict__ H, ushort_t* __restrict__ L,
                        const float* __restrict__ scale,
                        const float* __restrict__ shift) {
  int kq = Kp >> 2;
  long i = (long)blockIdx.x * 256 + threadIdx.x;
  if (i >= (long)R * kq) return;
  int r = (int)(i / kq);
  int k4 = (int)(i % kq) * 4;
  float vv[4] = {0.f, 0.f, 0.f, 0.f};
  if (k4 < K) {  // K % 4 == 0, no straddle
    float4 v = *(const float4*)(X + (long)r * K + k4);
    vv[0] = v.x; vv[1] = v.y; vv[2] = v.z; vv[3] = v.w;
    if (scale) {
#pragma unroll
      for (int t = 0; t < 4; t++)
        vv[t] = fmaxf(fmaf(vv[t], scale[k4 + t], shift[k4 + t]), 0.f);
    }
  }
  ushort_t h[4], l[4];
#pragma unroll
  for (int t = 0; t < 4; t++) {
    h[t] = f2bf(vv[t]);
    l[t] = f2bf(vv[t] - bf2f(h[t]));
  }
  long o = (long)r * Kp + k4;
  *(ushort2*)(H + o) = make_ushort2(h[0], h[1]);
  *(ushort2*)(H + o + 2) = make_ushort2(h[2], h[3]);
  *(ushort2*)(L + o) = make_ushort2(l[0], l[1]);
  *(ushort2*)(L + o + 2) = make_ushort2(l[2], l[3]);
}

// W [K][Nc] row-major -> transposed split H/L [Nc][Kp] (for B side of A@B^T)
__global__ void k_tsplit(const float* __restrict__ W, int K, int Nc, int Kp,
                         ushort_t* __restrict__ H, ushort_t* __restrict__ L) {
  int i = blockIdx.x * 256 + threadIdx.x;
  if (i >= Nc * Kp) return;
  int n = i / Kp, kp = i - n * Kp;
  float v = (kp < K) ? W[(long)kp * Nc + n] : 0.f;
  ushort_t h = f2bf(v);
  H[i] = h;
  L[i] = f2bf(v - bf2f(h));
}

// q[b][kp] = ent[subj[b]][kp] * rel_embed[rel[b]][kp], split to hi/lo, padded
__global__ void k_qsplit(const float* __restrict__ ent, const float* __restrict__ relE,
                         const int* __restrict__ subj, const int* __restrict__ rel,
                         ushort_t* __restrict__ H, ushort_t* __restrict__ L) {
  int i = blockIdx.x * 256 + threadIdx.x;
  if (i >= B_ * KP_D) return;
  int b = i / KP_D, kp = i - b * KP_D;
  float v = 0.f;
  if (kp < D_)
    v = ent[(long)subj[b] * D_ + kp] * relE[(long)rel[b] * D_ + kp];
  ushort_t h = f2bf(v);
  H[i] = h;
  L[i] = f2bf(v - bf2f(h));
}

// ---------------- MFMA split-bf16 GEMM: C[M,Nc] = A[M,K] @ Bm[Nc,K]^T ----------------
// 128x128 block tile, BK=32, 4 waves each owning 64x64 (4x4 fragments 16x16x32).
// A/B stored as hi/lo bf16 [*][Kp]. 3 MFMAs per fragment: hh + lh + hl.
// LDS: 4 buffers [128][32] bf16 (Ah|Al|Bh|Bl), staged via global_load_lds w=16,
// global source pre-swizzled with slot^=(row>>1)&3; reads use the same XOR ->
// 2-way bank access (free).
template <bool HAS_BIAS>
__global__ __launch_bounds__(256, 2) void k_mfma_abt(
    const ushort_t* __restrict__ Ah, const ushort_t* __restrict__ Al,
    const ushort_t* __restrict__ Bh, const ushort_t* __restrict__ Bl,
    float* __restrict__ C, int M, int Nc, int Kp, long ldc,
    const float* __restrict__ bias) {
  __shared__ ushort_t lds[4 * 128 * 32];
  const int tid = threadIdx.x;
  const int wave = tid >> 6, lane = tid & 63;
  const int bm = blockIdx.x * 128, bn = blockIdx.y * 128;
  const int wr = (wave >> 1) * 64, wc = (wave & 1) * 64;
  const int l15 = lane & 15, l4 = lane >> 4;

  f32x4 acc[4][4] = {};

  // staging geometry (constant over k-loop)
  const int r_st = ((wave * 8) & 7) * 16 + (lane >> 2);  // row within tile for j-chunks
  // note: chunk c = wave*8 + j ; rows depend on (c&7), buffer on (c>>3)

  for (int kc = 0; kc < Kp; kc += 32) {
#pragma unroll
    for (int j = 0; j < 8; ++j) {
      int c = wave * 8 + j;
      int buf = c >> 3;
      int r = (c & 7) * 16 + (lane >> 2);
      int sg = (lane & 3) ^ ((r >> 1) & 3);
      const ushort_t* bp;
      int rowg;
      if (buf == 0)      { bp = Ah; rowg = bm + r; if (rowg > M - 1) rowg = M - 1; }
      else if (buf == 1) { bp = Al; rowg = bm + r; if (rowg > M - 1) rowg = M - 1; }
      else if (buf == 2) { bp = Bh; rowg = bn + r; if (rowg > Nc - 1) rowg = Nc - 1; }
      else               { bp = Bl; rowg = bn + r; if (rowg > Nc - 1) rowg = Nc - 1; }
      const ushort_t* g = bp + (long)rowg * Kp + kc + sg * 8;
      gld16(g, lds + c * 512);
    }
    __syncthreads();

    bf16x8 a_h[4], a_l[4], b_h[4], b_l[4];
#pragma unroll
    for (int i = 0; i < 4; i++) {
      int rA = wr + i * 16 + l15;
      int sA = (l4 ^ ((rA >> 1) & 3)) * 8;
      a_h[i] = *(const bf16x8*)(lds + rA * 32 + sA);
      a_l[i] = *(const bf16x8*)(lds + 4096 + rA * 32 + sA);
      int rB = wc + i * 16 + l15;
      int sB = (l4 ^ ((rB >> 1) & 3)) * 8;
      b_h[i] = *(const bf16x8*)(lds + 8192 + rB * 32 + sB);
      b_l[i] = *(const bf16x8*)(lds + 12288 + rB * 32 + sB);
    }
#pragma unroll
    for (int i = 0; i < 4; i++)
#pragma unroll
      for (int j = 0; j < 4; j++) {
        acc[i][j] = __builtin_amdgcn_mfma_f32_16x16x32_bf16(a_h[i], b_h[j], acc[i][j], 0, 0, 0);
        acc[i][j] = __builtin_amdgcn_mfma_f32_16x16x32_bf16(a_l[i], b_h[j], acc[i][j], 0, 0, 0);
        acc[i][j] = __builtin_amdgcn_mfma_f32_16x16x32_bf16(a_h[i], b_l[j], acc[i][j], 0, 0, 0);
      }
    __syncthreads();
  }
  (void)r_st;

#pragma unroll
  for (int i = 0; i < 4; i++) {
    int mrow = bm + wr + i * 16 + l4 * 4;
#pragma unroll
    for (int j = 0; j < 4; j++) {
      int n = bn + wc + j * 16 + l15;
      if (n >= Nc) continue;
      float bb = HAS_BIAS ? bias[n] : 0.f;
#pragma unroll
      for (int v = 0; v < 4; v++) {
        int m = mrow + v;
        if (m < M) C[(long)m * ldc + n] = acc[i][j][v] + bb;
      }
    }
  }
}

// ---------------- small f32 GEMM (kept for tiny rel transforms) ----------------
template <int TM, int TN>
__global__ __launch_bounds__(256) void k_gemm_abt(
    const float* __restrict__ A, const float* __restrict__ Bm, float* __restrict__ C,
    int M, int Nc, int K, long ldc) {
  constexpr int BM = TM * 16, BN = TN * 16, KC = 20;
  __shared__ float As[BM * KC];
  __shared__ float Bs[BN * KC];
  const int tid = threadIdx.x;
  const int tx = tid & 15, ty = tid >> 4;
  const int bm = blockIdx.x * BM, bn = blockIdx.y * BN;
  float acc[TM][TN];
#pragma unroll
  for (int i = 0; i < TM; i++)
#pragma unroll
    for (int j = 0; j < TN; j++) acc[i][j] = 0.f;
  for (int kc = 0; kc < K; kc += KC) {
    for (int i4 = tid; i4 < BM * 5; i4 += 256) {
      int r = i4 / 5, kq = (i4 - r * 5) * 4;
      int row = bm + r; if (row > M - 1) row = M - 1;
      *(float4*)(As + r * KC + kq) = *(const float4*)(A + (long)row * K + kc + kq);
    }
    for (int i4 = tid; i4 < BN * 5; i4 += 256) {
      int r = i4 / 5, kq = (i4 - r * 5) * 4;
      int row = bn + r; if (row > Nc - 1) row = Nc - 1;
      *(float4*)(Bs + r * KC + kq) = *(const float4*)(Bm + (long)row * K + kc + kq);
    }
    __syncthreads();
#pragma unroll
    for (int k4 = 0; k4 < KC; k4 += 4) {
      float4 af[TM], bf[TN];
#pragma unroll
      for (int i = 0; i < TM; i++) af[i] = *(const float4*)(As + (i * 16 + ty) * KC + k4);
#pragma unroll
      for (int j = 0; j < TN; j++) bf[j] = *(const float4*)(Bs + (j * 16 + tx) * KC + k4);
#pragma unroll
      for (int i = 0; i < TM; i++)
#pragma unroll
        for (int j = 0; j < TN; j++) {
          acc[i][j] = fmaf(af[i].x, bf[j].x, acc[i][j]);
          acc[i][j] = fmaf(af[i].y, bf[j].y, acc[i][j]);
          acc[i][j] = fmaf(af[i].z, bf[j].z, acc[i][j]);
          acc[i][j] = fmaf(af[i].w, bf[j].w, acc[i][j]);
        }
    }
    __syncthreads();
  }
#pragma unroll
  for (int i = 0; i < TM; i++) {
    int m = bm + i * 16 + ty;
    if (m >= M) continue;
#pragma unroll
    for (int j = 0; j < TN; j++) {
      int n = bn + j * 16 + tx;
      if (n < Nc) C[(long)m * ldc + n] = acc[i][j];
    }
  }
}

__global__ void k_transpose(const float* __restrict__ s, float* __restrict__ d, int R, int C) {
  int i = blockIdx.x * 256 + threadIdx.x;
  if (i < R * C) { int r = i / C, c = i - r * C; d[c * R + r] = s[i]; }
}

// ---------------------------------------------------------------------------

extern "C" void kernel_launch(void* const* d_in, const int* in_sizes, int n_in,
                              void* d_out, int out_size, void* d_ws, size_t ws_size,
                              hipStream_t stream) {
  const int* src_id = (const int*)d_in[0];
  const int* dst_id = (const int*)d_in[1];
  const int* e_type = (const int*)d_in[2];
  const int* subj = (const int*)d_in[3];
  const int* rel = (const int*)d_in[4];
  const float* emb_h = (const float*)d_in[5];
  const float* emb_e = (const float*)d_in[6];
  const float* lin_w = (const float*)d_in[7];
  const float* lin_b = (const float*)d_in[8];
  const float* rel_wt = (const float*)d_in[9];
  const float* w_rel = (const float*)d_in[10];
  const float* agg_bn_g = (const float*)d_in[11];
  const float* agg_bn_b = (const float*)d_in[12];
  const float* cell_bn_g = (const float*)d_in[13];
  const float* cell_bn_b = (const float*)d_in[14];
  const float* concat_w = (const float*)d_in[15];
  const float* concat_b = (const float*)d_in[16];
  float* out = (float*)d_out;

  // ---- d_ws: only score-GEMM operands (read while d_out is written) ----
  char* w = (char*)d_ws;
  ushort_t* ent_h = (ushort_t*)(w + 0);           // 44,800,000
  ushort_t* ent_l = (ushort_t*)(w + 44800000);    // 44,800,000
  ushort_t* q_h   = (ushort_t*)(w + 89600000);    //    458,752
  ushort_t* q_l   = (ushort_t*)(w + 90112000);    //    458,752

  // ---- d_out front as temp (all dead before score GEMM) ----
  char* ob = (char*)d_out;
  float* ent    = (float*)(ob + 0);            // 80,000,000
  float* tmp    = (float*)(ob + 80000000);     // 80,000,000
  ushort_t* tmp_h = (ushort_t*)(ob + 160000000);  // 44,800,000
  ushort_t* tmp_l = (ushort_t*)(ob + 204800000);  // 44,800,000
  ushort_t* embh_h = (ushort_t*)(ob + 160000000); // 25,600,000 (init phase only)
  ushort_t* embh_l = (ushort_t*)(ob + 185600000); // 25,600,000
  int* counts  = (int*)(ob + 249600000);
  int* row_ptr = (int*)(ob + 250000000);
  int* cursor  = (int*)(ob + 250400000);
  int* csr_src = (int*)(ob + 250800000);       // 2,000,000
  int* csr_et  = (int*)(ob + 252800000);       // 2,000,000
  double* part = (double*)(ob + 254800000);    // 3,276,800
  float* relA  = (float*)(ob + 258100000);     //   380,000
  float* relB  = (float*)(ob + 258480000);     //   380,000
  float* embeT = (float*)(ob + 258860000);     //    80,000
  float* wrT   = (float*)(ob + 258940000);     //   160,000
  ushort_t* linw_h = (ushort_t*)(ob + 259100000);  // 51,200
  ushort_t* linw_l = (ushort_t*)(ob + 259151200);  // 51,200
  ushort_t* cw0_h  = (ushort_t*)(ob + 259202400);  // 89,600
  ushort_t* cw0_l  = (ushort_t*)(ob + 259292000);
  ushort_t* cw1_h  = (ushort_t*)(ob + 259381600);
  ushort_t* cw1_l  = (ushort_t*)(ob + 259471200);
  float* scaleb = (float*)(ob + 259560800);    // 896
  float* shiftb = (float*)(ob + 259561696);    // 896
  int* bsum     = (int*)(ob + 259562592);      // 512

  // ---- CSR build ----
  hipMemsetAsync(counts, 0, N_ENT * sizeof(int), stream);
  k_hist<<<(N_EF + 255) / 256, 256, 0, stream>>>(dst_id, counts);
  const int NB = (N_ENT + 1023) / 1024;  // 98
  k_scan_block<<<NB, 256, 0, stream>>>(counts, row_ptr, bsum);
  k_scan_tops<<<1, 256, 0, stream>>>(bsum, NB);
  k_scan_add<<<(N_ENT + 255) / 256, 256, 0, stream>>>(row_ptr, bsum, cursor);
  k_fill<<<(N_EF + 255) / 256, 256, 0, stream>>>(src_id, dst_id, e_type, cursor,
                                                 csr_src, csr_et);

  // ---- weight prep ----
  k_tsplit<<<(D_ * KP_D0 + 255) / 256, 256, 0, stream>>>(lin_w, D0_, D_, KP_D0,
                                                         linw_h, linw_l);
  k_tsplit<<<(D_ * KP_D + 255) / 256, 256, 0, stream>>>(concat_w, D_, D_, KP_D,
                                                        cw0_h, cw0_l);
  k_tsplit<<<(D_ * KP_D + 255) / 256, 256, 0, stream>>>(concat_w + D_ * D_, D_, D_,
                                                        KP_D, cw1_h, cw1_l);
  k_transpose<<<(D0_ * D_ + 255) / 256, 256, 0, stream>>>(emb_e, embeT, D0_, D_);
  k_transpose<<<(D_ * D_ + 255) / 256, 256, 0, stream>>>(w_rel, wrT, D_, D_);

  // ---- init projections ----
  const int GM = (N_ENT + 127) / 128;  // 782
  {  // emb_h split (K=100 -> Kp=128), then MFMA GEMM -> ent (f32) + lin_b
    long tot = (long)N_ENT * (KP_D0 / 4);
    k_split<<<(int)((tot + 255) / 256), 256, 0, stream>>>(emb_h, N_ENT, D0_, KP_D0,
                                                          embh_h, embh_l, nullptr, nullptr);
    k_mfma_abt<true><<<dim3(GM, 2), 256, 0, stream>>>(
        embh_h, embh_l, linw_h, linw_l, ent, N_ENT, D_, KP_D0, (long)D_, lin_b);
  }
  k_gemm_abt<8, 4><<<dim3(4, 4), 256, 0, stream>>>(rel_wt, embeT, relA, NREL_, D_,
                                                   D0_, (long)D_);

  float* relCur = relA;
  float* relNxt = relB;
  for (int i = 0; i < 2; i++) {
    k_aggregate<<<N_ENT, 256, 0, stream>>>(ent, relCur, row_ptr, counts, csr_src,
                                           csr_et, tmp);
    k_colstats<<<GSTAT, 256, 0, stream>>>(tmp, part);
    k_bn_fin<<<1, 256, 0, stream>>>(part, agg_bn_g + i * D_, agg_bn_b + i * D_,
                                    scaleb, shiftb);
    // BN+ReLU fused into split of tmp -> tmp_h/l
    long tot = (long)N_ENT * (KP_D / 4);
    k_split<<<(int)((tot + 255) / 256), 256, 0, stream>>>(tmp, N_ENT, D_, KP_D,
                                                          tmp_h, tmp_l, scaleb, shiftb);
    k_mfma_abt<true><<<dim3(GM, 2), 256, 0, stream>>>(
        tmp_h, tmp_l, (i == 0) ? cw0_h : cw1_h, (i == 0) ? cw0_l : cw1_l, ent,
        N_ENT, D_, KP_D, (long)D_, concat_b + i * D_);
    k_colstats<<<GSTAT, 256, 0, stream>>>(ent, part);
    k_bn_fin<<<1, 256, 0, stream>>>(part, cell_bn_g + i * D_, cell_bn_b + i * D_,
                                    scaleb, shiftb);
    k_norm_relu<<<2048, 256, 0, stream>>>(ent, scaleb, shiftb);
    k_gemm_abt<8, 4><<<dim3(4, 4), 256, 0, stream>>>(relCur, wrT, relNxt, NREL_, D_,
                                                     D_, (long)D_);
    float* t = relCur; relCur = relNxt; relNxt = t;
  }

  // ---- score operands into d_ws ----
  k_qsplit<<<(B_ * KP_D + 255) / 256, 256, 0, stream>>>(ent, relCur, subj, rel,
                                                        q_h, q_l);
  {
    long tot = (long)N_ENT * (KP_D / 4);
    k_split<<<(int)((tot + 255) / 256), 256, 0, stream>>>(ent, N_ENT, D_, KP_D,
                                                          ent_h, ent_l, nullptr, nullptr);
  }

  // ---- DistMult score: out[b][n], M=1024, Nc=100000 ----
  k_mfma_abt<false><<<dim3(B_ / 128, GM), 256, 0, stream>>>(
      q_h, q_l, ent_h, ent_l, out, B_, N_ENT, KP_D, (long)N_ENT, nullptr);
}

// Round 3
// 1122.789 us; speedup vs baseline: 1.8748x; 1.3614x over previous
//
#include <hip/hip_runtime.h>

// ---------------------------------------------------------------------------
// CompGCN-style network. GEMMs on MFMA (split-bf16 hi/lo, 3-term ~f32 accuracy).
//   N=100000 ents, E=400000 edges (+N self loops), D=200, D0=100,
//   NREL=475, B=1024 queries, L=2 layers
// Round 3: XCD-swizzled score GEMM, parallel bn_fin, norm+split fusion,
//          2-edge-unrolled aggregate.
// ---------------------------------------------------------------------------

#define N_ENT  100000
#define N_EDGE 400000
#define N_EF   500000
#define D_     200
#define D0_    100
#define NREL_  475
#define B_     1024
#define GSTAT  1024
#define KP_D   224   // D padded to multiple of 32
#define KP_D0  128   // D0 padded

typedef unsigned short ushort_t;
typedef __attribute__((ext_vector_type(8))) short bf16x8;
typedef __attribute__((ext_vector_type(4))) float f32x4;

__device__ __forceinline__ ushort_t f2bf(float x) {
  unsigned u = __float_as_uint(x);
  return (ushort_t)((u + 0x7FFFu + ((u >> 16) & 1u)) >> 16);
}
__device__ __forceinline__ float bf2f(ushort_t h) {
  return __uint_as_float(((unsigned)h) << 16);
}

__device__ __forceinline__ void gld16(const void* g, void* l) {
  __builtin_amdgcn_global_load_lds(
      (const __attribute__((address_space(1))) unsigned*)g,
      (__attribute__((address_space(3))) unsigned*)l, 16, 0, 0);
}

// ---------------- CSR build ----------------

__global__ void k_hist(const int* __restrict__ dst_id, int* __restrict__ cnt) {
  int e = blockIdx.x * 256 + threadIdx.x;
  if (e < N_EF) {
    int d = (e < N_EDGE) ? dst_id[e] : (e - N_EDGE);
    atomicAdd(&cnt[d], 1);
  }
}

__global__ __launch_bounds__(256) void k_scan_block(const int* __restrict__ cnt,
                                                    int* __restrict__ rp,
                                                    int* __restrict__ bsum) {
  __shared__ int sm[256];
  int tid = threadIdx.x;
  int base = blockIdx.x * 1024 + tid * 4;
  int v0 = (base + 0 < N_ENT) ? cnt[base + 0] : 0;
  int v1 = (base + 1 < N_ENT) ? cnt[base + 1] : 0;
  int v2 = (base + 2 < N_ENT) ? cnt[base + 2] : 0;
  int v3 = (base + 3 < N_ENT) ? cnt[base + 3] : 0;
  int tsum = v0 + v1 + v2 + v3;
  sm[tid] = tsum;
  __syncthreads();
  for (int off = 1; off < 256; off <<= 1) {
    int t = (tid >= off) ? sm[tid - off] : 0;
    __syncthreads();
    sm[tid] += t;
    __syncthreads();
  }
  int run = sm[tid] - tsum;
  if (base + 0 < N_ENT) { rp[base + 0] = run; } run += v0;
  if (base + 1 < N_ENT) { rp[base + 1] = run; } run += v1;
  if (base + 2 < N_ENT) { rp[base + 2] = run; } run += v2;
  if (base + 3 < N_ENT) { rp[base + 3] = run; }
  if (tid == 255) bsum[blockIdx.x] = sm[255];
}

__global__ void k_scan_tops(int* __restrict__ bsum, int nb) {
  __shared__ int sm[256];
  int tid = threadIdx.x;
  int v = (tid < nb) ? bsum[tid] : 0;
  sm[tid] = v;
  __syncthreads();
  for (int off = 1; off < 256; off <<= 1) {
    int t = (tid >= off) ? sm[tid - off] : 0;
    __syncthreads();
    sm[tid] += t;
    __syncthreads();
  }
  if (tid < nb) bsum[tid] = sm[tid] - v;
}

__global__ void k_scan_add(int* __restrict__ rp, const int* __restrict__ bsum,
                           int* __restrict__ cursor) {
  int i = blockIdx.x * 256 + threadIdx.x;
  if (i < N_ENT) {
    int r = rp[i] + bsum[i >> 10];
    rp[i] = r;
    cursor[i] = r;
  }
}

__global__ void k_fill(const int* __restrict__ src_id, const int* __restrict__ dst_id,
                       const int* __restrict__ e_type, int* __restrict__ cursor,
                       int* __restrict__ cs, int* __restrict__ ct) {
  int e = blockIdx.x * 256 + threadIdx.x;
  if (e < N_EF) {
    int s, d, t;
    if (e < N_EDGE) { s = src_id[e]; d = dst_id[e]; t = e_type[e]; }
    else            { s = e - N_EDGE; d = s; t = NREL_ - 1; }
    int pos = atomicAdd(&cursor[d], 1);
    cs[pos] = s;
    ct[pos] = t;
  }
}

// ---------------- aggregation / BN / misc ----------------

__global__ __launch_bounds__(256) void k_aggregate(const float* __restrict__ ent,
                                                   const float* __restrict__ relE,
                                                   const int* __restrict__ rp,
                                                   const int* __restrict__ cnt,
                                                   const int* __restrict__ cs,
                                                   const int* __restrict__ ct,
                                                   float* __restrict__ out) {
  int n = blockIdx.x;
  int f = threadIdx.x;
  if (f >= D_) return;
  int s0 = rp[n], e0 = s0 + cnt[n];
  float acc0 = 0.f, acc1 = 0.f;
  int idx = s0;
  for (; idx + 2 <= e0; idx += 2) {
    int sA = cs[idx], tA = ct[idx];
    int sB = cs[idx + 1], tB = ct[idx + 1];
    float eA = ent[(long)sA * D_ + f], rA = relE[(long)tA * D_ + f];
    float eB = ent[(long)sB * D_ + f], rB = relE[(long)tB * D_ + f];
    acc0 = fmaf(eA, rA, acc0);
    acc1 = fmaf(eB, rB, acc1);
  }
  if (idx < e0) {
    int sA = cs[idx], tA = ct[idx];
    acc0 = fmaf(ent[(long)sA * D_ + f], relE[(long)tA * D_ + f], acc0);
  }
  out[(long)n * D_ + f] = acc0 + acc1;
}

__global__ __launch_bounds__(256) void k_colstats(const float* __restrict__ X,
                                                  double* __restrict__ part) {
  int f = threadIdx.x;
  if (f >= D_) return;
  double s = 0.0, s2 = 0.0;
  for (int r = blockIdx.x; r < N_ENT; r += GSTAT) {
    float v = X[(long)r * D_ + f];
    s += v;
    s2 += (double)v * v;
  }
  part[(long)blockIdx.x * (2 * D_) + f] = s;
  part[(long)blockIdx.x * (2 * D_) + D_ + f] = s2;
}

// parallel deterministic reduction of part -> scale/shift (one block per feature)
__global__ __launch_bounds__(256) void k_bn_fin(const double* __restrict__ part,
                                                const float* __restrict__ g,
                                                const float* __restrict__ b,
                                                float* __restrict__ scale,
                                                float* __restrict__ shift) {
  int f = blockIdx.x;  // 0..D_-1
  int tid = threadIdx.x;
  double S = 0.0, S2 = 0.0;
  for (int i = tid; i < GSTAT; i += 256) {
    S += part[(long)i * (2 * D_) + f];
    S2 += part[(long)i * (2 * D_) + D_ + f];
  }
  __shared__ double smS[256], smS2[256];
  smS[tid] = S; smS2[tid] = S2;
  __syncthreads();
  for (int off = 128; off > 0; off >>= 1) {
    if (tid < off) { smS[tid] += smS[tid + off]; smS2[tid] += smS2[tid + off]; }
    __syncthreads();
  }
  if (tid == 0) {
    double mean = smS[0] / N_ENT;
    double var = smS2[0] / N_ENT - mean * mean;
    double inv = 1.0 / sqrt(var + 1e-5);
    float sc = g[f] * (float)inv;
    scale[f] = sc;
    shift[f] = b[f] - (float)mean * sc;
  }
}

// BN+ReLU in place; if SPLIT also emit bf16 hi/lo into padded [*][KP_D] buffers
template <bool SPLIT>
__global__ void k_norm_relu(float* __restrict__ X, const float* __restrict__ scale,
                            const float* __restrict__ shift,
                            ushort_t* __restrict__ H, ushort_t* __restrict__ L) {
  if (!SPLIT) {
    const long total = (long)N_ENT * D_ / 4;
    for (long i4 = (long)blockIdx.x * 256 + threadIdx.x; i4 < total;
         i4 += (long)gridDim.x * 256) {
      float4 v = ((float4*)X)[i4];
      int fb = (int)((i4 * 4) % D_);
      v.x = fmaxf(fmaf(v.x, scale[fb + 0], shift[fb + 0]), 0.f);
      v.y = fmaxf(fmaf(v.y, scale[fb + 1], shift[fb + 1]), 0.f);
      v.z = fmaxf(fmaf(v.z, scale[fb + 2], shift[fb + 2]), 0.f);
      v.w = fmaxf(fmaf(v.w, scale[fb + 3], shift[fb + 3]), 0.f);
      ((float4*)X)[i4] = v;
    }
  } else {
    const long total = (long)N_ENT * (KP_D / 4);
    for (long i4 = (long)blockIdx.x * 256 + threadIdx.x; i4 < total;
         i4 += (long)gridDim.x * 256) {
      int r = (int)(i4 / (KP_D / 4));
      int c4 = (int)(i4 % (KP_D / 4)) * 4;
      float vv[4] = {0.f, 0.f, 0.f, 0.f};
      if (c4 < D_) {
        float4 v = *(float4*)(X + (long)r * D_ + c4);
        vv[0] = fmaxf(fmaf(v.x, scale[c4 + 0], shift[c4 + 0]), 0.f);
        vv[1] = fmaxf(fmaf(v.y, scale[c4 + 1], shift[c4 + 1]), 0.f);
        vv[2] = fmaxf(fmaf(v.z, scale[c4 + 2], shift[c4 + 2]), 0.f);
        vv[3] = fmaxf(fmaf(v.w, scale[c4 + 3], shift[c4 + 3]), 0.f);
        float4 o = make_float4(vv[0], vv[1], vv[2], vv[3]);
        *(float4*)(X + (long)r * D_ + c4) = o;
      }
      unsigned hpack0, hpack1, lpack0, lpack1;
      ushort_t h[4], l[4];
#pragma unroll
      for (int t = 0; t < 4; t++) {
        h[t] = f2bf(vv[t]);
        l[t] = f2bf(vv[t] - bf2f(h[t]));
      }
      hpack0 = (unsigned)h[0] | ((unsigned)h[1] << 16);
      hpack1 = (unsigned)h[2] | ((unsigned)h[3] << 16);
      lpack0 = (unsigned)l[0] | ((unsigned)l[1] << 16);
      lpack1 = (unsigned)l[2] | ((unsigned)l[3] << 16);
      long o = (long)r * KP_D + c4;
      *(uint2*)(H + o) = make_uint2(hpack0, hpack1);
      *(uint2*)(L + o) = make_uint2(lpack0, lpack1);
    }
  }
}

// ---------------- split / convert kernels ----------------

// f32 [R][K] -> bf16 hi/lo [R][Kp], zero-padded; optional fused BN+ReLU.
__global__ void k_split(const float* __restrict__ X, int R, int K, int Kp,
                        ushort_t* __restrict__ H, ushort_t* __restrict__ L,
                        const float* __restrict__ scale,
                        const float* __restrict__ shift) {
  int kq = Kp >> 2;
  long i = (long)blockIdx.x * 256 + threadIdx.x;
  if (i >= (long)R * kq) return;
  int r = (int)(i / kq);
  int k4 = (int)(i % kq) * 4;
  float vv[4] = {0.f, 0.f, 0.f, 0.f};
  if (k4 < K) {  // K % 4 == 0, no straddle
    float4 v = *(const float4*)(X + (long)r * K + k4);
    vv[0] = v.x; vv[1] = v.y; vv[2] = v.z; vv[3] = v.w;
    if (scale) {
#pragma unroll
      for (int t = 0; t < 4; t++)
        vv[t] = fmaxf(fmaf(vv[t], scale[k4 + t], shift[k4 + t]), 0.f);
    }
  }
  ushort_t h[4], l[4];
#pragma unroll
  for (int t = 0; t < 4; t++) {
    h[t] = f2bf(vv[t]);
    l[t] = f2bf(vv[t] - bf2f(h[t]));
  }
  long o = (long)r * Kp + k4;
  *(uint2*)(H + o) = make_uint2((unsigned)h[0] | ((unsigned)h[1] << 16),
                                (unsigned)h[2] | ((unsigned)h[3] << 16));
  *(uint2*)(L + o) = make_uint2((unsigned)l[0] | ((unsigned)l[1] << 16),
                                (unsigned)l[2] | ((unsigned)l[3] << 16));
}

// W [K][Nc] row-major -> transposed split H/L [Nc][Kp] (for B side of A@B^T)
__global__ void k_tsplit(const float* __restrict__ W, int K, int Nc, int Kp,
                         ushort_t* __restrict__ H, ushort_t* __restrict__ L) {
  int i = blockIdx.x * 256 + threadIdx.x;
  if (i >= Nc * Kp) return;
  int n = i / Kp, kp = i - n * Kp;
  float v = (kp < K) ? W[(long)kp * Nc + n] : 0.f;
  ushort_t h = f2bf(v);
  H[i] = h;
  L[i] = f2bf(v - bf2f(h));
}

// q[b][kp] = ent[subj[b]][kp] * rel_embed[rel[b]][kp], split to hi/lo, padded
__global__ void k_qsplit(const float* __restrict__ ent, const float* __restrict__ relE,
                         const int* __restrict__ subj, const int* __restrict__ rel,
                         ushort_t* __restrict__ H, ushort_t* __restrict__ L) {
  int i = blockIdx.x * 256 + threadIdx.x;
  if (i >= B_ * KP_D) return;
  int b = i / KP_D, kp = i - b * KP_D;
  float v = 0.f;
  if (kp < D_)
    v = ent[(long)subj[b] * D_ + kp] * relE[(long)rel[b] * D_ + kp];
  ushort_t h = f2bf(v);
  H[i] = h;
  L[i] = f2bf(v - bf2f(h));
}

// ---------------- MFMA split-bf16 GEMM: C[M,Nc] = A[M,K] @ Bm[Nc,K]^T ----------------
// 128x128 block tile, BK=32, 4 waves each owning 64x64 (4x4 fragments 16x16x32).
// A/B stored as hi/lo bf16 [*][Kp]. 3 MFMAs per fragment: hh + lh + hl.
// LDS staged via global_load_lds w=16, pre-swizzled global source.
// SWZ: 1-D grid, XCD-aware decomposition (bn-tiles chunked per XCD; the 8
// q-chunks of one ent-tile land on the same XCD -> each ent tile fetched once).
template <bool HAS_BIAS, bool SWZ>
__global__ __launch_bounds__(256, 2) void k_mfma_abt(
    const ushort_t* __restrict__ Ah, const ushort_t* __restrict__ Al,
    const ushort_t* __restrict__ Bh, const ushort_t* __restrict__ Bl,
    float* __restrict__ C, int M, int Nc, int Kp, long ldc,
    const float* __restrict__ bias) {
  __shared__ ushort_t lds[4 * 128 * 32];
  const int tid = threadIdx.x;
  const int wave = tid >> 6, lane = tid & 63;
  int bxi, byi;
  if (SWZ) {
    int orig = blockIdx.x;
    int cpx = gridDim.x >> 3;                 // grid must be multiple of 8
    int swz = (orig & 7) * cpx + (orig >> 3); // XCD-contiguous linearization
    bxi = swz & 7;   // q-chunk  (M/128 == 8)
    byi = swz >> 3;  // ent tile
  } else {
    bxi = blockIdx.x;
    byi = blockIdx.y;
  }
  const int bm = bxi * 128, bn = byi * 128;
  const int wr = (wave >> 1) * 64, wc = (wave & 1) * 64;
  const int l15 = lane & 15, l4 = lane >> 4;

  f32x4 acc[4][4] = {};

  for (int kc = 0; kc < Kp; kc += 32) {
#pragma unroll
    for (int j = 0; j < 8; ++j) {
      int c = wave * 8 + j;
      int buf = c >> 3;
      int r = (c & 7) * 16 + (lane >> 2);
      int sg = (lane & 3) ^ ((r >> 1) & 3);
      const ushort_t* bp;
      int rowg;
      if (buf == 0)      { bp = Ah; rowg = bm + r; if (rowg > M - 1) rowg = M - 1; }
      else if (buf == 1) { bp = Al; rowg = bm + r; if (rowg > M - 1) rowg = M - 1; }
      else if (buf == 2) { bp = Bh; rowg = bn + r; if (rowg > Nc - 1) rowg = Nc - 1; }
      else               { bp = Bl; rowg = bn + r; if (rowg > Nc - 1) rowg = Nc - 1; }
      const ushort_t* g = bp + (long)rowg * Kp + kc + sg * 8;
      gld16(g, lds + c * 512);
    }
    __syncthreads();

    bf16x8 a_h[4], a_l[4], b_h[4], b_l[4];
#pragma unroll
    for (int i = 0; i < 4; i++) {
      int rA = wr + i * 16 + l15;
      int sA = (l4 ^ ((rA >> 1) & 3)) * 8;
      a_h[i] = *(const bf16x8*)(lds + rA * 32 + sA);
      a_l[i] = *(const bf16x8*)(lds + 4096 + rA * 32 + sA);
      int rB = wc + i * 16 + l15;
      int sB = (l4 ^ ((rB >> 1) & 3)) * 8;
      b_h[i] = *(const bf16x8*)(lds + 8192 + rB * 32 + sB);
      b_l[i] = *(const bf16x8*)(lds + 12288 + rB * 32 + sB);
    }
#pragma unroll
    for (int i = 0; i < 4; i++)
#pragma unroll
      for (int j = 0; j < 4; j++) {
        acc[i][j] = __builtin_amdgcn_mfma_f32_16x16x32_bf16(a_h[i], b_h[j], acc[i][j], 0, 0, 0);
        acc[i][j] = __builtin_amdgcn_mfma_f32_16x16x32_bf16(a_l[i], b_h[j], acc[i][j], 0, 0, 0);
        acc[i][j] = __builtin_amdgcn_mfma_f32_16x16x32_bf16(a_h[i], b_l[j], acc[i][j], 0, 0, 0);
      }
    __syncthreads();
  }

#pragma unroll
  for (int i = 0; i < 4; i++) {
    int mrow = bm + wr + i * 16 + l4 * 4;
#pragma unroll
    for (int j = 0; j < 4; j++) {
      int n = bn + wc + j * 16 + l15;
      if (n >= Nc) continue;
      float bb = HAS_BIAS ? bias[n] : 0.f;
#pragma unroll
      for (int v = 0; v < 4; v++) {
        int m = mrow + v;
        if (m < M) C[(long)m * ldc + n] = acc[i][j][v] + bb;
      }
    }
  }
}

// ---------------- small f32 GEMM (tiny rel transforms) ----------------
template <int TM, int TN>
__global__ __launch_bounds__(256) void k_gemm_abt(
    const float* __restrict__ A, const float* __restrict__ Bm, float* __restrict__ C,
    int M, int Nc, int K, long ldc) {
  constexpr int BM = TM * 16, BN = TN * 16, KC = 20;
  __shared__ float As[BM * KC];
  __shared__ float Bs[BN * KC];
  const int tid = threadIdx.x;
  const int tx = tid & 15, ty = tid >> 4;
  const int bm = blockIdx.x * BM, bn = blockIdx.y * BN;
  float acc[TM][TN];
#pragma unroll
  for (int i = 0; i < TM; i++)
#pragma unroll
    for (int j = 0; j < TN; j++) acc[i][j] = 0.f;
  for (int kc = 0; kc < K; kc += KC) {
    for (int i4 = tid; i4 < BM * 5; i4 += 256) {
      int r = i4 / 5, kq = (i4 - r * 5) * 4;
      int row = bm + r; if (row > M - 1) row = M - 1;
      *(float4*)(As + r * KC + kq) = *(const float4*)(A + (long)row * K + kc + kq);
    }
    for (int i4 = tid; i4 < BN * 5; i4 += 256) {
      int r = i4 / 5, kq = (i4 - r * 5) * 4;
      int row = bn + r; if (row > Nc - 1) row = Nc - 1;
      *(float4*)(Bs + r * KC + kq) = *(const float4*)(Bm + (long)row * K + kc + kq);
    }
    __syncthreads();
#pragma unroll
    for (int k4 = 0; k4 < KC; k4 += 4) {
      float4 af[TM], bf[TN];
#pragma unroll
      for (int i = 0; i < TM; i++) af[i] = *(const float4*)(As + (i * 16 + ty) * KC + k4);
#pragma unroll
      for (int j = 0; j < TN; j++) bf[j] = *(const float4*)(Bs + (j * 16 + tx) * KC + k4);
#pragma unroll
      for (int i = 0; i < TM; i++)
#pragma unroll
        for (int j = 0; j < TN; j++) {
          acc[i][j] = fmaf(af[i].x, bf[j].x, acc[i][j]);
          acc[i][j] = fmaf(af[i].y, bf[j].y, acc[i][j]);
          acc[i][j] = fmaf(af[i].z, bf[j].z, acc[i][j]);
          acc[i][j] = fmaf(af[i].w, bf[j].w, acc[i][j]);
        }
    }
    __syncthreads();
  }
#pragma unroll
  for (int i = 0; i < TM; i++) {
    int m = bm + i * 16 + ty;
    if (m >= M) continue;
#pragma unroll
    for (int j = 0; j < TN; j++) {
      int n = bn + j * 16 + tx;
      if (n < Nc) C[(long)m * ldc + n] = acc[i][j];
    }
  }
}

__global__ void k_transpose(const float* __restrict__ s, float* __restrict__ d, int R, int C) {
  int i = blockIdx.x * 256 + threadIdx.x;
  if (i < R * C) { int r = i / C, c = i - r * C; d[c * R + r] = s[i]; }
}

// ---------------------------------------------------------------------------

extern "C" void kernel_launch(void* const* d_in, const int* in_sizes, int n_in,
                              void* d_out, int out_size, void* d_ws, size_t ws_size,
                              hipStream_t stream) {
  const int* src_id = (const int*)d_in[0];
  const int* dst_id = (const int*)d_in[1];
  const int* e_type = (const int*)d_in[2];
  const int* subj = (const int*)d_in[3];
  const int* rel = (const int*)d_in[4];
  const float* emb_h = (const float*)d_in[5];
  const float* emb_e = (const float*)d_in[6];
  const float* lin_w = (const float*)d_in[7];
  const float* lin_b = (const float*)d_in[8];
  const float* rel_wt = (const float*)d_in[9];
  const float* w_rel = (const float*)d_in[10];
  const float* agg_bn_g = (const float*)d_in[11];
  const float* agg_bn_b = (const float*)d_in[12];
  const float* cell_bn_g = (const float*)d_in[13];
  const float* cell_bn_b = (const float*)d_in[14];
  const float* concat_w = (const float*)d_in[15];
  const float* concat_b = (const float*)d_in[16];
  float* out = (float*)d_out;

  // ---- d_ws: only score-GEMM operands (read while d_out is written) ----
  char* w = (char*)d_ws;
  ushort_t* ent_h = (ushort_t*)(w + 0);           // 44,800,000
  ushort_t* ent_l = (ushort_t*)(w + 44800000);    // 44,800,000
  ushort_t* q_h   = (ushort_t*)(w + 89600000);    //    458,752
  ushort_t* q_l   = (ushort_t*)(w + 90112000);    //    458,752

  // ---- d_out front as temp (all dead before score GEMM) ----
  char* ob = (char*)d_out;
  float* ent    = (float*)(ob + 0);            // 80,000,000
  float* tmp    = (float*)(ob + 80000000);     // 80,000,000
  ushort_t* tmp_h = (ushort_t*)(ob + 160000000);  // 44,800,000
  ushort_t* tmp_l = (ushort_t*)(ob + 204800000);  // 44,800,000
  ushort_t* embh_h = (ushort_t*)(ob + 160000000); // 25,600,000 (init phase only)
  ushort_t* embh_l = (ushort_t*)(ob + 185600000); // 25,600,000
  int* counts  = (int*)(ob + 249600000);
  int* row_ptr = (int*)(ob + 250000000);
  int* cursor  = (int*)(ob + 250400000);
  int* csr_src = (int*)(ob + 250800000);       // 2,000,000
  int* csr_et  = (int*)(ob + 252800000);       // 2,000,000
  double* part = (double*)(ob + 254800000);    // 3,276,800
  float* relA  = (float*)(ob + 258100000);     //   380,000
  float* relB  = (float*)(ob + 258480000);     //   380,000
  float* embeT = (float*)(ob + 258860000);     //    80,000
  float* wrT   = (float*)(ob + 258940000);     //   160,000
  ushort_t* linw_h = (ushort_t*)(ob + 259100000);  // 51,200
  ushort_t* linw_l = (ushort_t*)(ob + 259151200);  // 51,200
  ushort_t* cw0_h  = (ushort_t*)(ob + 259202400);  // 89,600
  ushort_t* cw0_l  = (ushort_t*)(ob + 259292000);
  ushort_t* cw1_h  = (ushort_t*)(ob + 259381600);
  ushort_t* cw1_l  = (ushort_t*)(ob + 259471200);
  float* scaleb = (float*)(ob + 259560800);    // 896
  float* shiftb = (float*)(ob + 259561696);    // 896
  int* bsum     = (int*)(ob + 259562592);      // 512

  // ---- CSR build ----
  hipMemsetAsync(counts, 0, N_ENT * sizeof(int), stream);
  k_hist<<<(N_EF + 255) / 256, 256, 0, stream>>>(dst_id, counts);
  const int NB = (N_ENT + 1023) / 1024;  // 98
  k_scan_block<<<NB, 256, 0, stream>>>(counts, row_ptr, bsum);
  k_scan_tops<<<1, 256, 0, stream>>>(bsum, NB);
  k_scan_add<<<(N_ENT + 255) / 256, 256, 0, stream>>>(row_ptr, bsum, cursor);
  k_fill<<<(N_EF + 255) / 256, 256, 0, stream>>>(src_id, dst_id, e_type, cursor,
                                                 csr_src, csr_et);

  // ---- weight prep ----
  k_tsplit<<<(D_ * KP_D0 + 255) / 256, 256, 0, stream>>>(lin_w, D0_, D_, KP_D0,
                                                         linw_h, linw_l);
  k_tsplit<<<(D_ * KP_D + 255) / 256, 256, 0, stream>>>(concat_w, D_, D_, KP_D,
                                                        cw0_h, cw0_l);
  k_tsplit<<<(D_ * KP_D + 255) / 256, 256, 0, stream>>>(concat_w + D_ * D_, D_, D_,
                                                        KP_D, cw1_h, cw1_l);
  k_transpose<<<(D0_ * D_ + 255) / 256, 256, 0, stream>>>(emb_e, embeT, D0_, D_);
  k_transpose<<<(D_ * D_ + 255) / 256, 256, 0, stream>>>(w_rel, wrT, D_, D_);

  // ---- init projections ----
  const int GM = (N_ENT + 127) / 128;  // 782
  {
    long tot = (long)N_ENT * (KP_D0 / 4);
    k_split<<<(int)((tot + 255) / 256), 256, 0, stream>>>(emb_h, N_ENT, D0_, KP_D0,
                                                          embh_h, embh_l, nullptr, nullptr);
    k_mfma_abt<true, false><<<dim3(GM, 2), 256, 0, stream>>>(
        embh_h, embh_l, linw_h, linw_l, ent, N_ENT, D_, KP_D0, (long)D_, lin_b);
  }
  k_gemm_abt<8, 4><<<dim3(4, 4), 256, 0, stream>>>(rel_wt, embeT, relA, NREL_, D_,
                                                   D0_, (long)D_);

  float* relCur = relA;
  float* relNxt = relB;
  for (int i = 0; i < 2; i++) {
    k_aggregate<<<N_ENT, 256, 0, stream>>>(ent, relCur, row_ptr, counts, csr_src,
                                           csr_et, tmp);
    k_colstats<<<GSTAT, 256, 0, stream>>>(tmp, part);
    k_bn_fin<<<D_, 256, 0, stream>>>(part, agg_bn_g + i * D_, agg_bn_b + i * D_,
                                     scaleb, shiftb);
    long tot = (long)N_ENT * (KP_D / 4);
    k_split<<<(int)((tot + 255) / 256), 256, 0, stream>>>(tmp, N_ENT, D_, KP_D,
                                                          tmp_h, tmp_l, scaleb, shiftb);
    k_mfma_abt<true, false><<<dim3(GM, 2), 256, 0, stream>>>(
        tmp_h, tmp_l, (i == 0) ? cw0_h : cw1_h, (i == 0) ? cw0_l : cw1_l, ent,
        N_ENT, D_, KP_D, (long)D_, concat_b + i * D_);
    k_colstats<<<GSTAT, 256, 0, stream>>>(ent, part);
    k_bn_fin<<<D_, 256, 0, stream>>>(part, cell_bn_g + i * D_, cell_bn_b + i * D_,
                                     scaleb, shiftb);
    if (i == 0) {
      k_norm_relu<false><<<2048, 256, 0, stream>>>(ent, scaleb, shiftb, nullptr, nullptr);
    } else {
      // fused: normalize ent in place AND emit padded hi/lo split for the score GEMM
      k_norm_relu<true><<<2048, 256, 0, stream>>>(ent, scaleb, shiftb, ent_h, ent_l);
    }
    k_gemm_abt<8, 4><<<dim3(4, 4), 256, 0, stream>>>(relCur, wrT, relNxt, NREL_, D_,
                                                     D_, (long)D_);
    float* t = relCur; relCur = relNxt; relNxt = t;
  }

  // ---- score operands: q split (ent_h/l already produced by fused norm) ----
  k_qsplit<<<(B_ * KP_D + 255) / 256, 256, 0, stream>>>(ent, relCur, subj, rel,
                                                        q_h, q_l);

  // ---- DistMult score: out[b][n], M=1024, Nc=100000, XCD-swizzled 1-D grid ----
  k_mfma_abt<false, true><<<dim3((B_ / 128) * GM), 256, 0, stream>>>(
      q_h, q_l, ent_h, ent_l, out, B_, N_ENT, KP_D, (long)N_ENT, nullptr);
}